// Round 1
// baseline (232.330 us; speedup 1.0000x reference)
//
#include <hip/hip_runtime.h>

#define B_ 2
#define H_ 16
#define SQ_ 2048
#define SKV_ 3072
#define DH 64
#define QT 64     // q rows per workgroup (4 waves x 16)
#define KVT 64    // kv tile
#define LDK 72    // padded LDS row stride (bf16 elems): 144B, 16B-aligned, 2-way-free banks

typedef __attribute__((ext_vector_type(4))) float f32x4;
typedef __attribute__((ext_vector_type(8))) short bf16x8;
typedef __attribute__((ext_vector_type(4))) short bf16x4;

__device__ __forceinline__ short f2bf(float f) {
  unsigned u = __float_as_uint(f);
  u += 0x7FFFu + ((u >> 16) & 1u);   // RNE; inputs are finite
  return (short)(u >> 16);
}

__global__ __launch_bounds__(256) void attn_fwd(
    const float* __restrict__ qg_, const float* __restrict__ kg_,
    const float* __restrict__ vg_, const int* __restrict__ num_pt_p,
    float* __restrict__ og_) {
  __shared__ __align__(16) short Ks[KVT][LDK];      // K tile [kv][d] bf16
  __shared__ __align__(16) short Vt[DH][LDK];       // V tile transposed [d][kv] bf16
  __shared__ __align__(16) short Ps[4][16][LDK];    // per-wave P [q][kv] bf16

  const int tid  = (int)threadIdx.x;
  const int lane = tid & 63;
  const int w    = tid >> 6;       // wave 0..3
  const int lq   = lane & 15;      // this lane's q-column (n index)
  const int quad = lane >> 4;      // 0..3
  const int nqb  = SQ_ / QT;
  const int qb   = nqb - 1 - (int)blockIdx.x;   // heavy-first
  const int bh   = (int)blockIdx.y;
  const int num_pt = *num_pt_p;
  const int q0   = qb * QT;

  const float* qg = qg_ + (size_t)bh * SQ_ * DH;
  const float* kg = kg_ + (size_t)bh * SKV_ * DH;
  const float* vg = vg_ + (size_t)bh * SKV_ * DH;
  float*       og = og_ + (size_t)bh * SQ_ * DH;

  // ---- Q as B-operand frags (Q^T): lane holds Q[q0+16w+lq][32*kh + 8*quad + j]
  const int qrow = q0 + w * 16 + lq;
  bf16x8 qf[2];
  {
    const float* qp = qg + (size_t)qrow * DH + quad * 8;
#pragma unroll
    for (int kh = 0; kh < 2; ++kh) {
      float4 a = *(const float4*)(qp + kh * 32);
      float4 b = *(const float4*)(qp + kh * 32 + 4);
      qf[kh][0] = f2bf(a.x * 0.125f);  // fold 1/sqrt(64): exact pow2 scale
      qf[kh][1] = f2bf(a.y * 0.125f);
      qf[kh][2] = f2bf(a.z * 0.125f);
      qf[kh][3] = f2bf(a.w * 0.125f);
      qf[kh][4] = f2bf(b.x * 0.125f);
      qf[kh][5] = f2bf(b.y * 0.125f);
      qf[kh][6] = f2bf(b.z * 0.125f);
      qf[kh][7] = f2bf(b.w * 0.125f);
    }
  }

  f32x4 O[4];
#pragma unroll
  for (int i = 0; i < 4; ++i) O[i] = (f32x4){0.f, 0.f, 0.f, 0.f};
  float m_run = -__builtin_inff();
  float l_run = 0.f;

  int n_tiles = (q0 + QT - 1 + num_pt) / KVT + 1;
  if (n_tiles > SKV_ / KVT) n_tiles = SKV_ / KVT;

  const int lim = qrow + num_pt;   // visible: kv <= lim

  for (int t = 0; t < n_tiles; ++t) {
    const int kb = t * KVT;
    __syncthreads();   // prior tile's LDS frag reads done before overwrite

    // ---- stage K tile: coalesced float4 loads, bf16 b64 LDS writes (4-way)
#pragma unroll
    for (int p = 0; p < 4; ++p) {
      int row = p * 16 + (tid >> 4);
      int col = (tid & 15) * 4;
      float4 f = *(const float4*)(kg + (size_t)(kb + row) * DH + col);
      bf16x4 h;
      h[0] = f2bf(f.x); h[1] = f2bf(f.y); h[2] = f2bf(f.z); h[3] = f2bf(f.w);
      *(bf16x4*)&Ks[row][col] = h;
    }
    // ---- stage V transposed: coalesced dword loads along d, b64 LDS writes
    {
      int d = tid & 63;
      int kq4 = (tid >> 6) * 4;
#pragma unroll
      for (int p = 0; p < 4; ++p) {
        int kvb = p * 16 + kq4;
        bf16x4 h;
#pragma unroll
        for (int i = 0; i < 4; ++i)
          h[i] = f2bf(vg[(size_t)(kb + kvb + i) * DH + d]);
        *(bf16x4*)&Vt[d][kvb] = h;
      }
    }
    __syncthreads();

    // ---- S^T = K · Q^T : st[mg][r] = S[q=lq][kv = kb + 16*mg + 4*quad + r]
    f32x4 st[4];
#pragma unroll
    for (int mg = 0; mg < 4; ++mg) {
      bf16x8 ka0 = *(const bf16x8*)&Ks[mg * 16 + lq][quad * 8];
      bf16x8 ka1 = *(const bf16x8*)&Ks[mg * 16 + lq][32 + quad * 8];
      f32x4 c = (f32x4){0.f, 0.f, 0.f, 0.f};
      c = __builtin_amdgcn_mfma_f32_16x16x32_bf16(ka0, qf[0], c, 0, 0, 0);
      c = __builtin_amdgcn_mfma_f32_16x16x32_bf16(ka1, qf[1], c, 0, 0, 0);
      st[mg] = c;
    }

    // ---- mask (only diagonal tile; wave-uniform branch)
    if (kb + KVT - 1 > q0 + w * 16 + num_pt) {
#pragma unroll
      for (int mg = 0; mg < 4; ++mg)
#pragma unroll
        for (int r = 0; r < 4; ++r) {
          int kvg = kb + mg * 16 + quad * 4 + r;
          if (kvg > lim) st[mg][r] = -__builtin_inff();
        }
    }

    // ---- online softmax for q = lq (16 in-lane + quads via shfl_xor 16/32)
    float mx = st[0][0];
#pragma unroll
    for (int mg = 0; mg < 4; ++mg)
#pragma unroll
      for (int r = 0; r < 4; ++r) mx = fmaxf(mx, st[mg][r]);
    mx = fmaxf(mx, __shfl_xor(mx, 16));
    mx = fmaxf(mx, __shfl_xor(mx, 32));
    float m_new = fmaxf(m_run, mx);
    float alpha = __expf(m_run - m_new);   // first tile: exp(-inf)=0
    float ts = 0.f;
#pragma unroll
    for (int mg = 0; mg < 4; ++mg)
#pragma unroll
      for (int r = 0; r < 4; ++r) {
        float pe = __expf(st[mg][r] - m_new);  // masked -> 0
        st[mg][r] = pe;
        ts += pe;
      }
    ts += __shfl_xor(ts, 16);
    ts += __shfl_xor(ts, 32);
    l_run = l_run * alpha + ts;
    m_run = m_new;

    // ---- P (C-layout of S^T) -> LDS [q][kv]: 4 regs = 4 consecutive kv = b64
    #pragma unroll
    for (int mg = 0; mg < 4; ++mg) {
      bf16x4 h;
#pragma unroll
      for (int r = 0; r < 4; ++r) h[r] = f2bf(st[mg][r]);
      *(bf16x4*)&Ps[w][lq][mg * 16 + quad * 4] = h;
    }

    // ---- rescale O rows by alpha (O row index = 4*quad + r; alpha lives at lane lq=row)
    float ar[4];
#pragma unroll
    for (int r = 0; r < 4; ++r) ar[r] = __shfl(alpha, quad * 4 + r);
#pragma unroll
    for (int dg = 0; dg < 4; ++dg)
#pragma unroll
      for (int r = 0; r < 4; ++r) O[dg][r] *= ar[r];

    // ---- O += P · V  (P as A-frag from LDS b128; V as B-frag from Vt b128)
    bf16x8 pa0 = *(const bf16x8*)&Ps[w][lq][quad * 8];
    bf16x8 pa1 = *(const bf16x8*)&Ps[w][lq][32 + quad * 8];
#pragma unroll
    for (int dg = 0; dg < 4; ++dg) {
      bf16x8 vb0 = *(const bf16x8*)&Vt[dg * 16 + lq][quad * 8];
      bf16x8 vb1 = *(const bf16x8*)&Vt[dg * 16 + lq][32 + quad * 8];
      O[dg] = __builtin_amdgcn_mfma_f32_16x16x32_bf16(pa0, vb0, O[dg], 0, 0, 0);
      O[dg] = __builtin_amdgcn_mfma_f32_16x16x32_bf16(pa1, vb1, O[dg], 0, 0, 0);
    }
  }

  // ---- epilogue: O / l, write fp32 (row = q0+16w+4*quad+r, col = 16*dg+lq)
  float inv[4];
#pragma unroll
  for (int r = 0; r < 4; ++r) {
    float lr = __shfl(l_run, quad * 4 + r);
    inv[r] = 1.0f / lr;
  }
#pragma unroll
  for (int dg = 0; dg < 4; ++dg)
#pragma unroll
    for (int r = 0; r < 4; ++r)
      og[(size_t)(q0 + w * 16 + quad * 4 + r) * DH + dg * 16 + lq] =
          O[dg][r] * inv[r];
}

extern "C" void kernel_launch(void* const* d_in, const int* in_sizes, int n_in,
                              void* d_out, int out_size, void* d_ws, size_t ws_size,
                              hipStream_t stream) {
  const float* q = (const float*)d_in[0];
  const float* k = (const float*)d_in[1];
  const float* v = (const float*)d_in[2];
  const int* np  = (const int*)d_in[3];
  float* out = (float*)d_out;
  dim3 grid(SQ_ / QT, B_ * H_);
  attn_fwd<<<grid, dim3(256), 0, stream>>>(q, k, v, np, out);
}

// Round 2
// 214.594 us; speedup vs baseline: 1.0827x; 1.0827x over previous
//
#include <hip/hip_runtime.h>

#define B_ 2
#define H_ 16
#define SQ_ 2048
#define SKV_ 3072
#define DH 64
#define QT 128    // q rows per workgroup (4 waves x 32)
#define KVT 64    // kv tile
#define LDK 72    // LDS row stride (shorts): 144B, 16B-aligned, conflict-free frag reads

typedef __attribute__((ext_vector_type(4))) float f32x4;
typedef __attribute__((ext_vector_type(8))) short bf16x8;

// pack two floats -> two bf16 (round-half-up) in one v_perm after two adds
__device__ __forceinline__ unsigned pk2(float a, float b) {
  return __builtin_amdgcn_perm(__float_as_uint(b) + 0x8000u,
                               __float_as_uint(a) + 0x8000u, 0x07060302u);
}
__device__ __forceinline__ short bf1(float a) {
  return (short)((__float_as_uint(a) + 0x8000u) >> 16);
}

__global__ __launch_bounds__(256) void attn_fwd(
    const float* __restrict__ qg_, const float* __restrict__ kg_,
    const float* __restrict__ vg_, const int* __restrict__ num_pt_p,
    float* __restrict__ og_) {
  __shared__ __align__(16) short Ks[KVT][LDK];     // K tile [kv][d]
  __shared__ __align__(16) short Vt[DH][LDK];      // V tile transposed [d][kv]
  __shared__ __align__(16) short Ps[4][32][LDK];   // per-wave P [q][kv]

  const int tid  = (int)threadIdx.x;
  const int lane = tid & 63;
  const int w    = tid >> 6;
  const int lq   = lane & 15;
  const int quad = lane >> 4;
  const int qb   = (SQ_ / QT) - 1 - (int)blockIdx.x;  // heavy-first
  const int bh   = (int)blockIdx.y;
  const int num_pt = *num_pt_p;
  const int q0   = qb * QT;

  const float* qg = qg_ + (size_t)bh * SQ_ * DH;
  const float* kg = kg_ + (size_t)bh * SKV_ * DH;
  const float* vg = vg_ + (size_t)bh * SKV_ * DH;
  float*       og = og_ + (size_t)bh * SQ_ * DH;

  const float SC = 0.125f * 1.44269504088896341f;  // fold 1/sqrt(64) * log2(e)

  // ---- Q as B-operand frags, scaled into log2 domain
  bf16x8 qf[2][2];
#pragma unroll
  for (int g = 0; g < 2; ++g) {
    const float* qp = qg + (size_t)(q0 + w * 32 + g * 16 + lq) * DH + quad * 8;
#pragma unroll
    for (int kh = 0; kh < 2; ++kh) {
      float4 a = *(const float4*)(qp + kh * 32);
      float4 b = *(const float4*)(qp + kh * 32 + 4);
      union { unsigned u[4]; bf16x8 h; } t;
      t.u[0] = pk2(a.x * SC, a.y * SC);
      t.u[1] = pk2(a.z * SC, a.w * SC);
      t.u[2] = pk2(b.x * SC, b.y * SC);
      t.u[3] = pk2(b.z * SC, b.w * SC);
      qf[g][kh] = t.h;
    }
  }

  f32x4 O[2][4];
#pragma unroll
  for (int g = 0; g < 2; ++g)
#pragma unroll
    for (int i = 0; i < 4; ++i) O[g][i] = (f32x4){0.f, 0.f, 0.f, 0.f};
  float m_run[2] = {-__builtin_inff(), -__builtin_inff()};
  float l_run[2] = {0.f, 0.f};

  int n_tiles = (q0 + QT - 1 + num_pt) / KVT + 1;
  if (n_tiles > SKV_ / KVT) n_tiles = SKV_ / KVT;

  // staging lane mapping
  const int krow = tid >> 4;          // 0..15 (K row within 16-group)
  const int kcol = (tid & 15) * 4;    // 0..60
  const int vkv  = tid & 63;          // V: one kv row per lane (clean LDS banks)
  const int vd0  = (tid >> 6) * 16;   // + p*4
  const float* kQp = kg + (size_t)krow * DH + kcol;
  const float* vQp = vg + (size_t)vkv * DH + vd0;

  float4 kf[4], vf[4];
#pragma unroll
  for (int p = 0; p < 4; ++p) {
    kf[p] = *(const float4*)(kQp + (size_t)(p * 16) * DH);
    vf[p] = *(const float4*)(vQp + p * 4);
  }

  for (int t = 0; t < n_tiles; ++t) {
    const int kb = t * KVT;
    __syncthreads();  // prior tile's frag reads done before overwrite

    // ---- write staged regs to LDS (bf16)
#pragma unroll
    for (int p = 0; p < 4; ++p) {
      *(uint2*)&Ks[p * 16 + krow][kcol] =
          make_uint2(pk2(kf[p].x, kf[p].y), pk2(kf[p].z, kf[p].w));
    }
#pragma unroll
    for (int p = 0; p < 4; ++p) {
      Vt[vd0 + p * 4 + 0][vkv] = bf1(vf[p].x);
      Vt[vd0 + p * 4 + 1][vkv] = bf1(vf[p].y);
      Vt[vd0 + p * 4 + 2][vkv] = bf1(vf[p].z);
      Vt[vd0 + p * 4 + 3][vkv] = bf1(vf[p].w);
    }
    // ---- prefetch next tile into regs (hidden behind compute)
    if (t + 1 < n_tiles) {
      const int nb = kb + KVT;
#pragma unroll
      for (int p = 0; p < 4; ++p) {
        kf[p] = *(const float4*)(kQp + (size_t)(nb + p * 16) * DH);
        vf[p] = *(const float4*)(vQp + (size_t)nb * DH + p * 4);
      }
    }
    __syncthreads();

    // ---- frag reads (shared across both q-groups)
    bf16x8 ka[4][2], vb[4][2];
#pragma unroll
    for (int mg = 0; mg < 4; ++mg) {
      ka[mg][0] = *(const bf16x8*)&Ks[mg * 16 + lq][quad * 8];
      ka[mg][1] = *(const bf16x8*)&Ks[mg * 16 + lq][32 + quad * 8];
      vb[mg][0] = *(const bf16x8*)&Vt[mg * 16 + lq][quad * 8];
      vb[mg][1] = *(const bf16x8*)&Vt[mg * 16 + lq][32 + quad * 8];
    }

#pragma unroll
    for (int g = 0; g < 2; ++g) {
      // S^T = K · Q^T  (log2 domain)
      f32x4 st[4];
#pragma unroll
      for (int mg = 0; mg < 4; ++mg) {
        f32x4 c = (f32x4){0.f, 0.f, 0.f, 0.f};
        c = __builtin_amdgcn_mfma_f32_16x16x32_bf16(ka[mg][0], qf[g][0], c, 0, 0, 0);
        c = __builtin_amdgcn_mfma_f32_16x16x32_bf16(ka[mg][1], qf[g][1], c, 0, 0, 0);
        st[mg] = c;
      }
      const int lim = q0 + w * 32 + g * 16 + lq + num_pt;
      if (kb + KVT - 1 > q0 + w * 32 + g * 16 + num_pt) {  // wave-uniform
#pragma unroll
        for (int mg = 0; mg < 4; ++mg)
#pragma unroll
          for (int r = 0; r < 4; ++r)
            if (kb + mg * 16 + quad * 4 + r > lim) st[mg][r] = -__builtin_inff();
      }
      // online softmax (base-2), stats per q=lq (in-lane for O^T)
      float mx = st[0][0];
#pragma unroll
      for (int mg = 0; mg < 4; ++mg)
#pragma unroll
        for (int r = 0; r < 4; ++r) mx = fmaxf(mx, st[mg][r]);
      mx = fmaxf(mx, __shfl_xor(mx, 16));
      mx = fmaxf(mx, __shfl_xor(mx, 32));
      float m_new = fmaxf(m_run[g], mx);
      float ts = 0.f;
#pragma unroll
      for (int mg = 0; mg < 4; ++mg)
#pragma unroll
        for (int r = 0; r < 4; ++r) {
          float pe = __builtin_amdgcn_exp2f(st[mg][r] - m_new);
          st[mg][r] = pe;
          ts += pe;
        }
      ts += __shfl_xor(ts, 16);
      ts += __shfl_xor(ts, 32);
      if (__any(m_new > m_run[g])) {
        float alpha = __builtin_amdgcn_exp2f(m_run[g] - m_new);
        l_run[g] = l_run[g] * alpha + ts;
        m_run[g] = m_new;
#pragma unroll
        for (int dg = 0; dg < 4; ++dg)
#pragma unroll
          for (int r = 0; r < 4; ++r) O[g][dg][r] *= alpha;
      } else {
        l_run[g] += ts;
      }
      // P -> LDS (same-wave round trip, no barrier)
#pragma unroll
      for (int mg = 0; mg < 4; ++mg) {
        *(uint2*)&Ps[w][g * 16 + lq][mg * 16 + quad * 4] =
            make_uint2(pk2(st[mg][0], st[mg][1]), pk2(st[mg][2], st[mg][3]));
      }
      bf16x8 pa0 = *(const bf16x8*)&Ps[w][g * 16 + lq][quad * 8];
      bf16x8 pa1 = *(const bf16x8*)&Ps[w][g * 16 + lq][32 + quad * 8];
      // O^T += V^T · P^T  (stats in-lane: col = q = lq)
#pragma unroll
      for (int dg = 0; dg < 4; ++dg) {
        O[g][dg] = __builtin_amdgcn_mfma_f32_16x16x32_bf16(vb[dg][0], pa0, O[g][dg], 0, 0, 0);
        O[g][dg] = __builtin_amdgcn_mfma_f32_16x16x32_bf16(vb[dg][1], pa1, O[g][dg], 0, 0, 0);
      }
    }
  }

  // ---- epilogue: O^T lane holds q=lq, d=dg*16+quad*4+r -> dwordx4 stores
#pragma unroll
  for (int g = 0; g < 2; ++g) {
    float inv = 1.0f / l_run[g];
    float* op = og + (size_t)(q0 + w * 32 + g * 16 + lq) * DH + quad * 4;
#pragma unroll
    for (int dg = 0; dg < 4; ++dg) {
      float4 o4;
      o4.x = O[g][dg][0] * inv;
      o4.y = O[g][dg][1] * inv;
      o4.z = O[g][dg][2] * inv;
      o4.w = O[g][dg][3] * inv;
      *(float4*)(op + dg * 16) = o4;
    }
  }
}

extern "C" void kernel_launch(void* const* d_in, const int* in_sizes, int n_in,
                              void* d_out, int out_size, void* d_ws, size_t ws_size,
                              hipStream_t stream) {
  const float* q = (const float*)d_in[0];
  const float* k = (const float*)d_in[1];
  const float* v = (const float*)d_in[2];
  const int* np  = (const int*)d_in[3];
  float* out = (float*)d_out;
  dim3 grid(SQ_ / QT, B_ * H_);
  attn_fwd<<<grid, dim3(256), 0, stream>>>(q, k, v, np, out);
}

// Round 3
// 187.457 us; speedup vs baseline: 1.2394x; 1.1448x over previous
//
#include <hip/hip_runtime.h>

#define B_ 2
#define H_ 16
#define SQ_ 2048
#define SKV_ 3072
#define DH 64
#define QT 128    // q rows per workgroup (8 waves x 16)
#define KVT 64    // kv tile
#define LDK 72    // LDS row stride (shorts): 144B; 2-way-max bank aliasing on all access patterns

typedef __attribute__((ext_vector_type(4))) float f32x4;
typedef __attribute__((ext_vector_type(8))) short bf16x8;

// pack two floats -> two bf16 (round-half-up) in one v_perm after two adds
__device__ __forceinline__ unsigned pk2(float a, float b) {
  return __builtin_amdgcn_perm(__float_as_uint(b) + 0x8000u,
                               __float_as_uint(a) + 0x8000u, 0x07060302u);
}
__device__ __forceinline__ short bf1(float a) {
  return (short)((__float_as_uint(a) + 0x8000u) >> 16);
}

__global__ __launch_bounds__(512, 4) void attn_fwd(
    const float* __restrict__ qg_, const float* __restrict__ kg_,
    const float* __restrict__ vg_, const int* __restrict__ num_pt_p,
    float* __restrict__ og_) {
  __shared__ __align__(16) short Ks[KVT][LDK];     // K tile [kv][d]
  __shared__ __align__(16) short Vt[DH][LDK];      // V tile transposed [d][kv]
  __shared__ __align__(16) short Ps[8][16][LDK];   // per-wave P [q][kv]

  const int tid  = (int)threadIdx.x;
  const int lane = tid & 63;
  const int w    = tid >> 6;       // wave 0..7
  const int lq   = lane & 15;
  const int quad = lane >> 4;
  const int qb   = (SQ_ / QT) - 1 - (int)blockIdx.x;  // heavy-first
  const int bh   = (int)blockIdx.y;
  const int num_pt = *num_pt_p;
  const int q0   = qb * QT;

  const float* qg = qg_ + (size_t)bh * SQ_ * DH;
  const float* kg = kg_ + (size_t)bh * SKV_ * DH;
  const float* vg = vg_ + (size_t)bh * SKV_ * DH;
  float*       og = og_ + (size_t)bh * SQ_ * DH;

  const float SC = 0.125f * 1.44269504088896341f;  // 1/sqrt(64) * log2(e)

  // ---- Q as B-operand frags (wave w owns q rows q0+16w .. +15), log2 domain
  const int qrow = q0 + w * 16 + lq;
  bf16x8 qf[2];
  {
    const float* qp = qg + (size_t)qrow * DH + quad * 8;
#pragma unroll
    for (int kh = 0; kh < 2; ++kh) {
      float4 a = *(const float4*)(qp + kh * 32);
      float4 b = *(const float4*)(qp + kh * 32 + 4);
      union { unsigned u[4]; bf16x8 h; } t;
      t.u[0] = pk2(a.x * SC, a.y * SC);
      t.u[1] = pk2(a.z * SC, a.w * SC);
      t.u[2] = pk2(b.x * SC, b.y * SC);
      t.u[3] = pk2(b.z * SC, b.w * SC);
      qf[kh] = t.h;
    }
  }

  f32x4 O[4];
#pragma unroll
  for (int i = 0; i < 4; ++i) O[i] = (f32x4){0.f, 0.f, 0.f, 0.f};
  float m_run = -__builtin_inff();
  float l_run = 0.f;   // per-lane partial (this lane's 16 kv slots); reduced at end

  int n_tiles = (q0 + QT - 1 + num_pt) / KVT + 1;
  if (n_tiles > SKV_ / KVT) n_tiles = SKV_ / KVT;

  // staging lane mapping (512 threads, 8 floats each)
  const int krow = tid >> 3;          // 0..63
  const int kcol = (tid & 7) * 8;     // 0..56
  const int vkv  = tid & 63;          // one kv row per lane
  const int vd0  = (tid >> 6) * 8;    // wave w covers d in [8w, 8w+8)
  const float* kQp = kg + (size_t)krow * DH + kcol;
  const float* vQp = vg + (size_t)vkv * DH + vd0;

  float4 kf[2], vf[2];
  kf[0] = *(const float4*)(kQp);
  kf[1] = *(const float4*)(kQp + 4);
  vf[0] = *(const float4*)(vQp);
  vf[1] = *(const float4*)(vQp + 4);

  const int lim = qrow + num_pt;   // visible: kv <= lim

  for (int t = 0; t < n_tiles; ++t) {
    const int kb = t * KVT;
    __syncthreads();  // prior tile's frag reads done before overwrite

    // ---- write staged regs to LDS (bf16): K one b128/thread, V 8 scalars
    {
      union { unsigned u[4]; bf16x8 h; } tk;
      tk.u[0] = pk2(kf[0].x, kf[0].y);
      tk.u[1] = pk2(kf[0].z, kf[0].w);
      tk.u[2] = pk2(kf[1].x, kf[1].y);
      tk.u[3] = pk2(kf[1].z, kf[1].w);
      *(bf16x8*)&Ks[krow][kcol] = tk.h;
      Vt[vd0 + 0][vkv] = bf1(vf[0].x);
      Vt[vd0 + 1][vkv] = bf1(vf[0].y);
      Vt[vd0 + 2][vkv] = bf1(vf[0].z);
      Vt[vd0 + 3][vkv] = bf1(vf[0].w);
      Vt[vd0 + 4][vkv] = bf1(vf[1].x);
      Vt[vd0 + 5][vkv] = bf1(vf[1].y);
      Vt[vd0 + 6][vkv] = bf1(vf[1].z);
      Vt[vd0 + 7][vkv] = bf1(vf[1].w);
    }
    // ---- prefetch next tile into regs (hidden behind compute)
    if (t + 1 < n_tiles) {
      const size_t nb = (size_t)(kb + KVT) * DH;
      kf[0] = *(const float4*)(kQp + nb);
      kf[1] = *(const float4*)(kQp + nb + 4);
      vf[0] = *(const float4*)(vQp + nb);
      vf[1] = *(const float4*)(vQp + nb + 4);
    }
    __syncthreads();

    // ---- S^T = K · Q^T  (log2 domain)
    f32x4 st[4];
#pragma unroll
    for (int mg = 0; mg < 4; ++mg) {
      bf16x8 ka0 = *(const bf16x8*)&Ks[mg * 16 + lq][quad * 8];
      bf16x8 ka1 = *(const bf16x8*)&Ks[mg * 16 + lq][32 + quad * 8];
      f32x4 c = (f32x4){0.f, 0.f, 0.f, 0.f};
      c = __builtin_amdgcn_mfma_f32_16x16x32_bf16(ka0, qf[0], c, 0, 0, 0);
      c = __builtin_amdgcn_mfma_f32_16x16x32_bf16(ka1, qf[1], c, 0, 0, 0);
      st[mg] = c;
    }

    // ---- mask (diagonal tile only; wave-uniform branch)
    if (kb + KVT - 1 > q0 + w * 16 + num_pt) {
#pragma unroll
      for (int mg = 0; mg < 4; ++mg)
#pragma unroll
        for (int r = 0; r < 4; ++r)
          if (kb + mg * 16 + quad * 4 + r > lim) st[mg][r] = -__builtin_inff();
    }

    // ---- online softmax (base-2), stats per q=lq (in-lane for O^T)
    float mx = st[0][0];
#pragma unroll
    for (int mg = 0; mg < 4; ++mg)
#pragma unroll
      for (int r = 0; r < 4; ++r) mx = fmaxf(mx, st[mg][r]);
    mx = fmaxf(mx, __shfl_xor(mx, 16));
    mx = fmaxf(mx, __shfl_xor(mx, 32));
    float m_new = fmaxf(m_run, mx);
    float ts = 0.f;
#pragma unroll
    for (int mg = 0; mg < 4; ++mg)
#pragma unroll
      for (int r = 0; r < 4; ++r) {
        float pe = __builtin_amdgcn_exp2f(st[mg][r] - m_new);
        st[mg][r] = pe;
        ts += pe;
      }
    if (__any(m_new > m_run)) {
      float alpha = __builtin_amdgcn_exp2f(m_run - m_new);
      l_run = l_run * alpha + ts;
      m_run = m_new;
#pragma unroll
      for (int dg = 0; dg < 4; ++dg)
#pragma unroll
        for (int r = 0; r < 4; ++r) O[dg][r] *= alpha;
    } else {
      l_run += ts;
    }

    // ---- P -> LDS (same-wave round trip, no barrier)
#pragma unroll
    for (int mg = 0; mg < 4; ++mg) {
      *(uint2*)&Ps[w][lq][mg * 16 + quad * 4] =
          make_uint2(pk2(st[mg][0], st[mg][1]), pk2(st[mg][2], st[mg][3]));
    }
    bf16x8 pa0 = *(const bf16x8*)&Ps[w][lq][quad * 8];
    bf16x8 pa1 = *(const bf16x8*)&Ps[w][lq][32 + quad * 8];
    // ---- O^T += V^T · P^T (stats in-lane: C col = q = lq)
#pragma unroll
    for (int dg = 0; dg < 4; ++dg) {
      bf16x8 vb0 = *(const bf16x8*)&Vt[dg * 16 + lq][quad * 8];
      bf16x8 vb1 = *(const bf16x8*)&Vt[dg * 16 + lq][32 + quad * 8];
      O[dg] = __builtin_amdgcn_mfma_f32_16x16x32_bf16(vb0, pa0, O[dg], 0, 0, 0);
      O[dg] = __builtin_amdgcn_mfma_f32_16x16x32_bf16(vb1, pa1, O[dg], 0, 0, 0);
    }
  }

  // ---- epilogue: reduce l across quads, O^T lane holds q=lq, d=dg*16+quad*4+r
  l_run += __shfl_xor(l_run, 16);
  l_run += __shfl_xor(l_run, 32);
  float inv = 1.0f / l_run;
  float* op = og + (size_t)qrow * DH + quad * 4;
#pragma unroll
  for (int dg = 0; dg < 4; ++dg) {
    float4 o4;
    o4.x = O[dg][0] * inv;
    o4.y = O[dg][1] * inv;
    o4.z = O[dg][2] * inv;
    o4.w = O[dg][3] * inv;
    *(float4*)(op + dg * 16) = o4;
  }
}

extern "C" void kernel_launch(void* const* d_in, const int* in_sizes, int n_in,
                              void* d_out, int out_size, void* d_ws, size_t ws_size,
                              hipStream_t stream) {
  const float* q = (const float*)d_in[0];
  const float* k = (const float*)d_in[1];
  const float* v = (const float*)d_in[2];
  const int* np  = (const int*)d_in[3];
  float* out = (float*)d_out;
  dim3 grid(SQ_ / QT, B_ * H_);
  attn_fwd<<<grid, dim3(512), 0, stream>>>(q, k, v, np, out);
}